// Round 7
// baseline (40.908 us; speedup 1.0000x reference)
//
#include <hip/hip_runtime.h>
#include <hip/hip_bf16.h>

// T=256, B=8, H1=512, U=64, H2=512, V=128
// out[b,t,u,v] = f[t,b,:]·W[:512,v] + g[b,u,:]·W[512:,v] + bias[v]; f_lens tail.
// Single fused kernel, 256 blocks = (b, 8 t-rows), no workspace, no cross-block deps.
// Per block: pg panel computed redundantly (32x, cheap), pf for 8 rows; both via
// LDS-staged bf16 MFMA; store phase streams 256 KB coalesced.
// R4/R5 lesson: no in-kernel cross-block sync (agent fences nuke write BW).
// R6 lesson: kernel boundaries + P round-trip (cross-XCD dirty reads) cost ~10 us.

typedef float  f32x2 __attribute__((ext_vector_type(2)));
typedef float  f32x4 __attribute__((ext_vector_type(4)));
typedef short  bh8   __attribute__((ext_vector_type(8)));

__device__ __forceinline__ unsigned short f2bf(float x) {
    unsigned u = __float_as_uint(x);
    return (unsigned short)((u + 0x7FFFu + ((u >> 16) & 1u)) >> 16);
}

__device__ __forceinline__ bh8 cvt8(f32x4 a, f32x4 b) {
    bh8 r;
    r[0] = (short)f2bf(a[0]); r[1] = (short)f2bf(a[1]);
    r[2] = (short)f2bf(a[2]); r[3] = (short)f2bf(a[3]);
    r[4] = (short)f2bf(b[0]); r[5] = (short)f2bf(b[1]);
    r[6] = (short)f2bf(b[2]); r[7] = (short)f2bf(b[3]);
    return r;
}

__global__ __launch_bounds__(256) void joint(const float* __restrict__ F,
                                             const float* __restrict__ G,
                                             const float* __restrict__ W,
                                             const float* __restrict__ bias,
                                             const int* __restrict__ f_lens,
                                             float* __restrict__ out,
                                             int lens_off) {
    __shared__ short Bf[2][4][128][8];   // 16 KB: dbuf x kq x v x k8 (W[:512] slice)
    __shared__ short Bg[2][4][128][8];   // 16 KB: same for W[512:]
    __shared__ float pgs[64][128];       // 32 KB
    __shared__ float pfs[8][128];        //  4 KB

    const int tid = threadIdx.x;
    const int b  = blockIdx.x >> 5;
    const int t0 = (blockIdx.x & 31) * 8;
    const int w = tid >> 6, lane = tid & 63, l15 = lane & 15, cg = lane >> 4;

    // staging: thread -> (kq = w, two v's), 8 k-rows per step
    const int v0 = (tid & 63) * 2;
    // A row pointers
    const float* grow = G + (b * 64 + w * 16 + l15) * 512;            // pg: 16 distinct u
    const float* frow = F + ((t0 + (l15 & 7)) * 8 + b) * 512;         // pf: 8 rows dup x2

    f32x4 accg[8] = {};
    f32x4 accf[2] = {};

    // ---- prologue: stage step 0 into buffer 0 ----
    {
        const int krow = w * 8;
        short tf[2][8], tg[2][8];
#pragma unroll
        for (int r = 0; r < 8; ++r) {
            f32x2 xf = *reinterpret_cast<const f32x2*>(W + (krow + r) * 128 + v0);
            f32x2 xg = *reinterpret_cast<const f32x2*>(W + (512 + krow + r) * 128 + v0);
            tf[0][r] = (short)f2bf(xf[0]); tf[1][r] = (short)f2bf(xf[1]);
            tg[0][r] = (short)f2bf(xg[0]); tg[1][r] = (short)f2bf(xg[1]);
        }
#pragma unroll
        for (int i = 0; i < 2; ++i) {
            *reinterpret_cast<bh8*>(&Bf[0][w][v0 + i][0]) = *reinterpret_cast<bh8*>(&tf[i][0]);
            *reinterpret_cast<bh8*>(&Bg[0][w][v0 + i][0]) = *reinterpret_cast<bh8*>(&tg[i][0]);
        }
    }
    __syncthreads();

    // ---- main loop: 16 K-steps of 32 ----
    for (int s = 0; s < 16; ++s) {
        const int d = s & 1;
        if (s < 15) {                                  // stage next step
            const int krow = (s + 1) * 32 + w * 8;
            short tf[2][8], tg[2][8];
#pragma unroll
            for (int r = 0; r < 8; ++r) {
                f32x2 xf = *reinterpret_cast<const f32x2*>(W + (krow + r) * 128 + v0);
                f32x2 xg = *reinterpret_cast<const f32x2*>(W + (512 + krow + r) * 128 + v0);
                tf[0][r] = (short)f2bf(xf[0]); tf[1][r] = (short)f2bf(xf[1]);
                tg[0][r] = (short)f2bf(xg[0]); tg[1][r] = (short)f2bf(xg[1]);
            }
#pragma unroll
            for (int i = 0; i < 2; ++i) {
                *reinterpret_cast<bh8*>(&Bf[d ^ 1][w][v0 + i][0]) = *reinterpret_cast<bh8*>(&tf[i][0]);
                *reinterpret_cast<bh8*>(&Bg[d ^ 1][w][v0 + i][0]) = *reinterpret_cast<bh8*>(&tg[i][0]);
            }
        }

        const int k0 = s * 32 + cg * 8;
        // pg: wave-owned u-tile, full K
        f32x4 g0 = *reinterpret_cast<const f32x4*>(grow + k0);
        f32x4 g1 = *reinterpret_cast<const f32x4*>(grow + k0 + 4);
        bh8 ag = cvt8(g0, g1);
#pragma unroll
        for (int j = 0; j < 8; ++j) {
            bh8 bb = *reinterpret_cast<const bh8*>(&Bg[d][cg][j * 16 + l15][0]);
            accg[j] = __builtin_amdgcn_mfma_f32_16x16x32_bf16(ag, bb, accg[j], 0, 0, 0);
        }
        // pf: j-split (cols 2w, 2w+1), full K, no reduce
        f32x4 f0 = *reinterpret_cast<const f32x4*>(frow + k0);
        f32x4 f1 = *reinterpret_cast<const f32x4*>(frow + k0 + 4);
        bh8 af = cvt8(f0, f1);
#pragma unroll
        for (int jj = 0; jj < 2; ++jj) {
            bh8 bb = *reinterpret_cast<const bh8*>(&Bf[d][cg][(2 * w + jj) * 16 + l15][0]);
            accf[jj] = __builtin_amdgcn_mfma_f32_16x16x32_bf16(af, bb, accf[jj], 0, 0, 0);
        }
        __syncthreads();
    }

    // ---- results to LDS ----
#pragma unroll
    for (int j = 0; j < 8; ++j)
#pragma unroll
        for (int q = 0; q < 4; ++q)
            pgs[w * 16 + cg * 4 + q][j * 16 + l15] = accg[j][q];
    if (cg < 2) {                                     // rows 8-15 are duplicates
#pragma unroll
        for (int jj = 0; jj < 2; ++jj)
#pragma unroll
            for (int q = 0; q < 4; ++q)
                pfs[cg * 4 + q][(2 * w + jj) * 16 + l15] = accf[jj][q];
    }
    __syncthreads();

    // ---- store phase: 256 KB coalesced ----
    const int vq = tid & 31, ug = tid >> 5;
    const f32x4 bi = *reinterpret_cast<const f32x4*>(bias + vq * 4);
    f32x4 pfv[8];
#pragma unroll
    for (int t2 = 0; t2 < 8; ++t2)
        pfv[t2] = *reinterpret_cast<const f32x4*>(&pfs[t2][vq * 4]) + bi;

    float* ob = out + (size_t)(b * 256 + t0) * 8192;
#pragma unroll
    for (int ui = 0; ui < 8; ++ui) {
        const int u = ui * 8 + ug;
        f32x4 pgv = *reinterpret_cast<const f32x4*>(&pgs[u][vq * 4]);
#pragma unroll
        for (int t2 = 0; t2 < 8; ++t2)
            *reinterpret_cast<f32x4*>(ob + (t2 * 64 + u) * 128 + vq * 4) = pfv[t2] + pgv;
    }

    if (blockIdx.x == 0 && tid < 8) out[lens_off + tid] = (float)f_lens[tid];
}

extern "C" void kernel_launch(void* const* d_in, const int* in_sizes, int n_in,
                              void* d_out, int out_size, void* d_ws, size_t ws_size,
                              hipStream_t stream) {
    const float* f      = (const float*)d_in[0];
    const int*   f_lens = (const int*)  d_in[1];
    const float* g      = (const float*)d_in[2];
    // d_in[3] = g_lens (unused by reference output)
    const float* W      = (const float*)d_in[4];
    const float* bias   = (const float*)d_in[5];
    float* out = (float*)d_out;

    joint<<<dim3(256), dim3(256), 0, stream>>>(f, g, W, bias, f_lens, out, out_size - 8);
}